// Round 4
// baseline (7715.135 us; speedup 1.0000x reference)
//
#include <hip/hip_runtime.h>
#include <hip/hip_bf16.h>

typedef unsigned short u16;
typedef __attribute__((ext_vector_type(8)))  short  short8;
typedef __attribute__((ext_vector_type(16))) float  f32x16;

#define MB     256      // batch
#define SRCT   120      // encoder steps
#define DECT   24       // decoder steps
#define NSTEP  (SRCT + DECT)
#define DIN    216      // input dim
#define HDIM   1024     // hidden
#define KXP    224      // padded x segment (216 real + 8 zero)
#define KA     1248     // KXP + HDIM
#define NGATE  4096     // 4*HDIM
#define OUTD   216
#define KCH    96       // K per LDS chunk (6 mfma k-tiles)
#define NCHUNK 13       // 13*96 = 1248
#define GP     65       // gates LDS pitch (64+1)
#define NWG    256

// ---- ws layout (bytes) ----
#define OFF_SRCBF 0u                        // [256][120][224] bf16 = 13,762,560
#define OFF_H     13762560u                 // [2][256][1024] bf16 =  1,048,576
#define OFF_XDEC  14811136u                 // [256][224] bf16     =    114,688
#define OFF_WCAT  14925824u                 // [4096][1248] bf16   = 10,223,616
#define OFF_WO    25149440u                 // [216][1024] bf16    =    442,368
#define OFF_BAR   25591808u                 // 16 uints

__device__ __forceinline__ u16 f2bf(float f) {
    union { float f; unsigned v; } c; c.f = f;
    return (u16)((c.v + 0x7FFFu + ((c.v >> 16) & 1u)) >> 16);
}
__device__ __forceinline__ float sigm(float x)  { return 1.0f / (1.0f + __expf(-x)); }
__device__ __forceinline__ float tanh_(float x) { return 1.0f - 2.0f / (1.0f + __expf(2.0f * x)); }

// device-scope barrier: monotone counter, gen*NWG target. AGENT-scope
// acquire emits the L1/L2 invalidate needed for cross-XCD visibility.
__device__ __forceinline__ void gbar(unsigned* bar, unsigned gen) {
    __syncthreads();
    if (threadIdx.x == 0) {
        __threadfence();
        __hip_atomic_fetch_add(bar, 1u, __ATOMIC_ACQ_REL, __HIP_MEMORY_SCOPE_AGENT);
        const unsigned target = gen * NWG;
        while (__hip_atomic_load(bar, __ATOMIC_ACQUIRE, __HIP_MEMORY_SCOPE_AGENT) < target)
            __builtin_amdgcn_s_sleep(2);
    }
    __syncthreads();
}

// ---------------- prep: convert fp32 inputs -> bf16 working buffers ----------------
__global__ void prep_kernel(const float* __restrict__ src,
                            const float* __restrict__ W_ih,
                            const float* __restrict__ W_hh,
                            const float* __restrict__ W_out,
                            u16* __restrict__ srcbf, u16* __restrict__ H,
                            u16* __restrict__ Xdec,  u16* __restrict__ Wcat,
                            u16* __restrict__ Wo,    unsigned* __restrict__ bar) {
    const int nS  = MB * SRCT * KXP;   // srcbf (with zero pads)
    const int nW  = NGATE * KA;        // Wcat
    const int nWo = OUTD * HDIM;       // Wo
    const int nH  = MB * HDIM;         // H buf0 = 0
    const int nXp = MB * 8;            // Xdec pad cols
    const int total = nS + nW + nWo + nH + nXp + 16;
    for (int i = blockIdx.x * blockDim.x + threadIdx.x; i < total; i += gridDim.x * blockDim.x) {
        if (i < nS) {
            int b = i / (SRCT * KXP), r = i % (SRCT * KXP);
            int t = r / KXP, col = r % KXP;
            srcbf[i] = (col < DIN) ? f2bf(src[((size_t)b * SRCT + t) * DIN + col]) : (u16)0;
        } else if (i < nS + nW) {
            int j = i - nS;
            int r = j / KA, col = j % KA;
            u16 v = 0;
            if (col < DIN)       v = f2bf(W_ih[(size_t)r * DIN + col]);
            else if (col >= KXP) v = f2bf(W_hh[(size_t)r * HDIM + (col - KXP)]);
            Wcat[j] = v;
        } else if (i < nS + nW + nWo) {
            int j = i - nS - nW;
            Wo[j] = f2bf(W_out[j]);
        } else if (i < nS + nW + nWo + nH) {
            H[i - nS - nW - nWo] = 0;
        } else if (i < nS + nW + nWo + nH + nXp) {
            int j = i - nS - nW - nWo - nH;
            Xdec[(j >> 3) * KXP + DIN + (j & 7)] = 0;
        } else {
            bar[i - nS - nW - nWo - nH - nXp] = 0;
        }
    }
}

// ---------------- persistent LSTM ----------------
// grid 256 = 4 M-tiles x 64 N-tiles. WG tile: [64 M x 64 gate-cols],
// gate-cols = 16 hcols (nj*16..) x {i,f,g,o}. Wave = one 32x32 mfma tile.
__global__ void __launch_bounds__(256, 1)
lstm_persist(const u16* __restrict__ srcbf, u16* __restrict__ H,
             u16* __restrict__ Xdec, const u16* __restrict__ Wcat,
             const u16* __restrict__ Wo,
             const float* __restrict__ b_ih, const float* __restrict__ b_hh,
             const float* __restrict__ b_out,
             float* __restrict__ dout, unsigned* __restrict__ bar)
{
    __shared__ u16 Ach[2][12 * 64 * 8];   // [k-octet][m][8], double buffered
    __shared__ float G[64 * GP];

    const int bid  = blockIdx.x;
    const int mi   = bid >> 6;     // 0..3
    const int nj   = bid & 63;     // 0..63
    const int m0   = mi * 64;
    const int tid  = threadIdx.x;
    const int w    = tid >> 6;
    const int lane = tid & 63;
    const int msub = w & 1;
    const int nsub = w >> 1;
    const int l31  = lane & 31;
    const int kg   = lane >> 5;

    // gate-GEMM B row for this lane
    const int ncol = nsub * 32 + l31;
    const int gate = ncol >> 4;
    const int rowg = gate * 1024 + nj * 16 + (ncol & 15);
    const u16* pw  = Wcat + (size_t)rowg * KA;

    const int arow = msub * 32 + l31;

    // pointwise mapping: thread -> (m-local, 4 hcols); c + biases in registers
    const int pm = tid & 63;
    const int pb = (tid >> 6) * 4;
    float creg[4] = {0.f, 0.f, 0.f, 0.f};
    float bI[4], bF[4], bG[4], bO[4];
#pragma unroll
    for (int e = 0; e < 4; ++e) {
        int hc = nj * 16 + pb + e;
        bI[e] = b_ih[hc]        + b_hh[hc];
        bF[e] = b_ih[1024 + hc] + b_hh[1024 + hc];
        bG[e] = b_ih[2048 + hc] + b_hh[2048 + hc];
        bO[e] = b_ih[3072 + hc] + b_hh[3072 + hc];
    }

    unsigned gen = 0;

    for (int t = 0; t < NSTEP; ++t) {
        const u16* Hc = H + (size_t)(t & 1) * MB * HDIM;
        u16*       Hn = H + (size_t)((t + 1) & 1) * MB * HDIM;
        const u16* xbase; int xstr;
        if (t <= SRCT) {   // encoder x, and first decoder x = src[:, -1, :]
            int tt = (t < SRCT) ? t : (SRCT - 1);
            xbase = srcbf + (size_t)tt * KXP; xstr = SRCT * KXP;
        } else {
            xbase = Xdec; xstr = KXP;
        }

        f32x16 acc0 = {}; f32x16 acc1 = {};

        // stage chunk 0
#pragma unroll
        for (int s = 0; s < 3; ++s) {
            int flat = tid + s * 256;
            int cs = flat >> 6, row = flat & 63;
            int cb = cs * 8;
            const u16* sp = (cb < KXP) ? xbase + (size_t)(m0 + row) * xstr + cb
                                       : Hc + (size_t)(m0 + row) * HDIM + (cb - KXP);
            *(uint4*)&Ach[0][cs * 512 + row * 8] = *(const uint4*)sp;
        }
        __syncthreads();

        int p = 0;
        for (int ch = 0; ch < NCHUNK; ++ch) {
            uint4 stg[3];
            if (ch < NCHUNK - 1) {
#pragma unroll
                for (int s = 0; s < 3; ++s) {
                    int flat = tid + s * 256;
                    int cs = flat >> 6, row = flat & 63;
                    int cb = (ch + 1) * KCH + cs * 8;
                    const u16* sp = (cb < KXP) ? xbase + (size_t)(m0 + row) * xstr + cb
                                               : Hc + (size_t)(m0 + row) * HDIM + (cb - KXP);
                    stg[s] = *(const uint4*)sp;
                }
            }
#pragma unroll
            for (int j = 0; j < 6; ++j) {
                const int k = ch * KCH + j * 16;
                short8 af = *(const short8*)&Ach[p][(2 * j + kg) * 512 + arow * 8];
                short8 bf = *(const short8*)(pw + k + kg * 8);
                if (j & 1) acc1 = __builtin_amdgcn_mfma_f32_32x32x16_bf16(af, bf, acc1, 0, 0, 0);
                else       acc0 = __builtin_amdgcn_mfma_f32_32x32x16_bf16(af, bf, acc0, 0, 0, 0);
            }
            if (ch < NCHUNK - 1) {
#pragma unroll
                for (int s = 0; s < 3; ++s) {
                    int flat = tid + s * 256;
                    int cs = flat >> 6, row = flat & 63;
                    *(uint4*)&Ach[p ^ 1][cs * 512 + row * 8] = stg[s];
                }
            }
            __syncthreads();
            p ^= 1;
        }

        // gates -> LDS (C/D layout: col = lane&31, row = (r&3)+8*(r>>2)+4*kg)
#pragma unroll
        for (int r = 0; r < 16; ++r) {
            int grow = (r & 3) + 8 * (r >> 2) + 4 * kg;
            G[(msub * 32 + grow) * GP + nsub * 32 + l31] = acc0[r] + acc1[r];
        }
        __syncthreads();

        // pointwise cell: c fp32 in regs, h -> bf16 into Hn
#pragma unroll
        for (int e = 0; e < 4; ++e) {
            int hc = pb + e;
            float gi = G[pm * GP + hc]      + bI[e];
            float gf = G[pm * GP + 16 + hc] + bF[e];
            float gg = G[pm * GP + 32 + hc] + bG[e];
            float go = G[pm * GP + 48 + hc] + bO[e];
            float c  = sigm(gf) * creg[e] + sigm(gi) * tanh_(gg);
            creg[e]  = c;
            Hn[(size_t)(m0 + pm) * HDIM + nj * 16 + hc] = f2bf(sigm(go) * tanh_(c));
        }

        gbar(bar, ++gen);

        if (t >= SRCT) {
            const int d = t - SRCT;
            if (bid < 14) {
                const int tile = bid * 4 + w;   // 56 tiles = 8 M x 7 N (216->224)
                const int mt = tile & 7;
                const int nt = tile >> 3;
                const int am = mt * 32 + l31;
                const int bn = nt * 32 + l31;
                const int brow = (bn < OUTD) ? bn : (OUTD - 1);
                f32x16 oa0 = {}; f32x16 oa1 = {};
                const u16* ah = Hn + (size_t)am * HDIM + kg * 8;
                const u16* bw = Wo + (size_t)brow * HDIM + kg * 8;
#pragma unroll 4
                for (int kt = 0; kt < 64; ++kt) {
                    short8 af = *(const short8*)(ah + kt * 16);
                    short8 bf = *(const short8*)(bw + kt * 16);
                    if (kt & 1) oa1 = __builtin_amdgcn_mfma_f32_32x32x16_bf16(af, bf, oa1, 0, 0, 0);
                    else        oa0 = __builtin_amdgcn_mfma_f32_32x32x16_bf16(af, bf, oa0, 0, 0, 0);
                }
                if (bn < OUTD) {
                    float bo = b_out[bn];
#pragma unroll
                    for (int r = 0; r < 16; ++r) {
                        int grow = (r & 3) + 8 * (r >> 2) + 4 * kg;
                        int mm = mt * 32 + grow;
                        float v = oa0[r] + oa1[r] + bo;
                        dout[(size_t)mm * (DECT * OUTD) + d * OUTD + bn] = v;
                        Xdec[(size_t)mm * KXP + bn] = f2bf(v);   // next decoder x
                    }
                }
            }
            gbar(bar, ++gen);
        }
    }
}

extern "C" void kernel_launch(void* const* d_in, const int* in_sizes, int n_in,
                              void* d_out, int out_size, void* d_ws, size_t ws_size,
                              hipStream_t stream) {
    const float* src   = (const float*)d_in[0];
    // d_in[1] = tgt (unused in eval forward)
    const float* W_ih  = (const float*)d_in[2];
    const float* W_hh  = (const float*)d_in[3];
    const float* b_ih  = (const float*)d_in[4];
    const float* b_hh  = (const float*)d_in[5];
    const float* W_out = (const float*)d_in[6];
    const float* b_out = (const float*)d_in[7];
    float* out = (float*)d_out;

    char* ws = (char*)d_ws;
    u16*      srcbf = (u16*)(ws + OFF_SRCBF);
    u16*      H     = (u16*)(ws + OFF_H);
    u16*      Xdec  = (u16*)(ws + OFF_XDEC);
    u16*      Wcat  = (u16*)(ws + OFF_WCAT);
    u16*      Wo    = (u16*)(ws + OFF_WO);
    unsigned* bar   = (unsigned*)(ws + OFF_BAR);

    hipLaunchKernelGGL(prep_kernel, dim3(1024), dim3(256), 0, stream,
                       src, W_ih, W_hh, W_out, srcbf, H, Xdec, Wcat, Wo, bar);

    hipLaunchKernelGGL(lstm_persist, dim3(NWG), dim3(256), 0, stream,
                       srcbf, H, Xdec, Wcat, Wo, b_ih, b_hh, b_out, out, bar);
}

// Round 5
// 4514.609 us; speedup vs baseline: 1.7089x; 1.7089x over previous
//
#include <hip/hip_runtime.h>
#include <hip/hip_bf16.h>

typedef unsigned short u16;
typedef __attribute__((ext_vector_type(8)))  short  short8;
typedef __attribute__((ext_vector_type(16))) float  f32x16;

#define MB     256      // batch
#define SRCT   120      // encoder steps
#define DECT   24       // decoder steps
#define NSTEP  (SRCT + DECT)
#define DIN    216      // input dim
#define HDIM   1024     // hidden
#define KXP    224      // padded x segment (216 real + 8 zero)
#define KA     1248     // KXP + HDIM
#define NGATE  4096
#define OUTD   216
#define NKT    78       // 16-wide K tiles (1248/16)
#define NOCT   156      // 8-wide k-octets
#define NWG    256

// ---- ws layout (bytes) ----
#define OFF_SRCBF 0u                 // [256][120][224] bf16 = 13,762,560
#define OFF_H     13762560u          // [2][256][1024] bf16  =  1,048,576
#define OFF_XDEC  14811136u          // [256][224] bf16      =    114,688
#define OFF_WCAT  14925824u          // [4096][1248] bf16    = 10,223,616
#define OFF_WO    25149440u          // [216][1024] bf16     =    442,368
#define OFF_BAR   25591808u          // 8 counters spaced 64 B = 512 B

__device__ __forceinline__ u16 f2bf(float f) {
    union { float f; unsigned v; } c; c.f = f;
    return (u16)((c.v + 0x7FFFu + ((c.v >> 16) & 1u)) >> 16);
}
__device__ __forceinline__ float sigm(float x)  { return 1.0f / (1.0f + __expf(-x)); }
__device__ __forceinline__ float tanh_(float x) { return 1.0f - 2.0f / (1.0f + __expf(2.0f * x)); }

// group-local (32-WG) device barrier. Release fence + RMW, acquire polls.
__device__ __forceinline__ void gbar(unsigned* ctr, unsigned target) {
    __syncthreads();
    if (threadIdx.x == 0) {
        __threadfence();
        __hip_atomic_fetch_add(ctr, 1u, __ATOMIC_ACQ_REL, __HIP_MEMORY_SCOPE_AGENT);
        while (__hip_atomic_load(ctr, __ATOMIC_ACQUIRE, __HIP_MEMORY_SCOPE_AGENT) < target)
            __builtin_amdgcn_s_sleep(2);
    }
    __syncthreads();
}

// ---------------- prep: convert fp32 inputs -> bf16 working buffers ----------------
__global__ void prep_kernel(const float* __restrict__ src,
                            const float* __restrict__ W_ih,
                            const float* __restrict__ W_hh,
                            const float* __restrict__ W_out,
                            u16* __restrict__ srcbf, u16* __restrict__ H,
                            u16* __restrict__ Xdec,  u16* __restrict__ Wcat,
                            u16* __restrict__ Wo,    unsigned* __restrict__ bar) {
    const int nS  = MB * SRCT * KXP;
    const int nW  = NGATE * KA;
    const int nWo = OUTD * HDIM;
    const int nH  = MB * HDIM;     // H buf0 = 0
    const int nXp = MB * 8;        // Xdec pad cols
    const int total = nS + nW + nWo + nH + nXp + 128;
    for (int i = blockIdx.x * blockDim.x + threadIdx.x; i < total; i += gridDim.x * blockDim.x) {
        if (i < nS) {
            int b = i / (SRCT * KXP), r = i % (SRCT * KXP);
            int t = r / KXP, col = r % KXP;
            srcbf[i] = (col < DIN) ? f2bf(src[((size_t)b * SRCT + t) * DIN + col]) : (u16)0;
        } else if (i < nS + nW) {
            int j = i - nS;
            int r = j / KA, col = j % KA;
            u16 v = 0;
            if (col < DIN)       v = f2bf(W_ih[(size_t)r * DIN + col]);
            else if (col >= KXP) v = f2bf(W_hh[(size_t)r * HDIM + (col - KXP)]);
            Wcat[j] = v;
        } else if (i < nS + nW + nWo) {
            Wo[i - nS - nW] = f2bf(W_out[i - nS - nW]);
        } else if (i < nS + nW + nWo + nH) {
            H[i - nS - nW - nWo] = 0;
        } else if (i < nS + nW + nWo + nH + nXp) {
            int j = i - nS - nW - nWo - nH;
            Xdec[(j >> 3) * KXP + DIN + (j & 7)] = 0;
        } else {
            bar[i - nS - nW - nWo - nH - nXp] = 0;
        }
    }
}

// ---------------- persistent LSTM, weights pinned in VGPRs ----------------
// 256 WGs: group g = bid&7 owns batches [g*32, g*32+32); slice s = bid>>3 owns
// h-cols [s*32, s*32+32) x 4 gates. Wave w = gate type w. 8 independent
// 32-WG barrier domains; groups share no data (only read-only weights).
__global__ void __launch_bounds__(256, 1)
lstm_persist(const u16* __restrict__ srcbf, u16* __restrict__ H,
             u16* __restrict__ Xdec, const u16* __restrict__ Wcat,
             const u16* __restrict__ Wo,
             const float* __restrict__ b_ih, const float* __restrict__ b_hh,
             const float* __restrict__ b_out,
             float* __restrict__ dout, unsigned* __restrict__ bar)
{
    __shared__ u16  Ach[NOCT * 32 * 8];   // [koct][m][8]  79,872 B
    __shared__ float G[4][32][33];        // gate/partial exchange, 16,896 B

    const int bid  = blockIdx.x;
    const int g    = bid & 7;
    const int s    = bid >> 3;
    const int b0   = g * 32;
    const int tid  = threadIdx.x;
    const int w    = tid >> 6;     // wave = gate type (i,f,g,o)
    const int lane = tid & 63;
    const int l31  = lane & 31;
    const int kg   = lane >> 5;

    unsigned* myctr = bar + g * 16;   // 64 B apart

    // ---- pin this wave's weight slice in VGPRs (loaded once) ----
    short8 Bfrag[NKT];
    {
        const int wrow = w * 1024 + s * 32 + l31;          // W row for this lane's col
        const u16* pw = Wcat + (size_t)wrow * KA + kg * 8;
#pragma unroll
        for (int kt = 0; kt < NKT; ++kt)
            Bfrag[kt] = *(const short8*)(pw + kt * 16);
    }

    // pointwise mapping: thread -> (batch pm, 4 h-cols); biases + c in regs
    const int pm = tid & 31;
    const int hb = tid >> 5;       // 0..7
    float creg[4], bI[4], bF[4], bG_[4], bO[4], bOut[4];
#pragma unroll
    for (int e = 0; e < 4; ++e) {
        creg[e] = 0.f;
        int hcg = s * 32 + hb * 4 + e;
        bI[e]  = b_ih[hcg]        + b_hh[hcg];
        bF[e]  = b_ih[1024 + hcg] + b_hh[1024 + hcg];
        bG_[e] = b_ih[2048 + hcg] + b_hh[2048 + hcg];
        bO[e]  = b_ih[3072 + hcg] + b_hh[3072 + hcg];
        bOut[e] = (s < 7 && hcg < OUTD) ? b_out[hcg] : 0.f;   // hcg doubles as out-col
    }

    unsigned gen = 0;

    for (int t = 0; t < NSTEP; ++t) {
        const u16* Hc = H + (size_t)(t & 1) * MB * HDIM;
        u16*       Hn = H + (size_t)((t + 1) & 1) * MB * HDIM;
        const u16* xrow; int xstr;
        if (t <= SRCT) {   // encoder x; t==SRCT: first decoder x = src[:,119,:]
            int tt = (t < SRCT) ? t : (SRCT - 1);
            xrow = srcbf + (size_t)tt * KXP; xstr = SRCT * KXP;
        } else {
            xrow = Xdec; xstr = KXP;
        }

        // ---- stage A = [x|h] (32 batches x 1248) into LDS [koct][m][8] ----
#pragma unroll 4
        for (int i = 0; i < 20; ++i) {
            int f = tid + i * 256;
            if (f < NOCT * 32) {
                int oct = f >> 5, m = f & 31;
                int k0 = oct * 8;
                const u16* sp = (k0 < KXP) ? xrow + (size_t)(b0 + m) * xstr + k0
                                           : Hc + (size_t)(b0 + m) * HDIM + (k0 - KXP);
                *(uint4*)&Ach[(size_t)f * 8] = *(const uint4*)sp;
            }
        }
        __syncthreads();

        // ---- gate GEMM: 78 MFMAs vs pinned B ----
        f32x16 acc0 = {}; f32x16 acc1 = {};
#pragma unroll
        for (int kt = 0; kt < NKT; ++kt) {
            short8 af = *(const short8*)&Ach[(((2 * kt + kg) << 5) + l31) * 8];
            if (kt & 1) acc1 = __builtin_amdgcn_mfma_f32_32x32x16_bf16(af, Bfrag[kt], acc1, 0, 0, 0);
            else        acc0 = __builtin_amdgcn_mfma_f32_32x32x16_bf16(af, Bfrag[kt], acc0, 0, 0, 0);
        }

        // gates -> LDS (C/D layout: col=lane&31, row=(r&3)+8*(r>>2)+4*kg)
#pragma unroll
        for (int r = 0; r < 16; ++r) {
            int grow = (r & 3) + 8 * (r >> 2) + 4 * kg;
            G[w][grow][l31] = acc0[r] + acc1[r];
        }
        __syncthreads();

        // ---- pointwise cell; h (4 bf16) packed into one 8 B store ----
        {
            u16 hv[4];
#pragma unroll
            for (int e = 0; e < 4; ++e) {
                int hcl = hb * 4 + e;
                float gi = G[0][pm][hcl] + bI[e];
                float gf = G[1][pm][hcl] + bF[e];
                float gg = G[2][pm][hcl] + bG_[e];
                float go = G[3][pm][hcl] + bO[e];
                float c  = sigm(gf) * creg[e] + sigm(gi) * tanh_(gg);
                creg[e]  = c;
                hv[e] = f2bf(sigm(go) * tanh_(c));
            }
            *(uint2*)&Hn[(size_t)(b0 + pm) * HDIM + s * 32 + hb * 4] = *(const uint2*)hv;
        }

        gbar(myctr, ++gen * 32);

        // ---- decoder: out = h_new @ W_out^T + b_out (7 slices/group work) ----
        if (t >= SRCT) {
            const int d = t - SRCT;
            if (s < 7) {
                const int ocg0 = s * 32 + l31;
                const int ocr  = (ocg0 < OUTD) ? ocg0 : (OUTD - 1);
                const u16* ph  = Hn + (size_t)(b0 + l31) * HDIM + kg * 8;
                const u16* pwo = Wo + (size_t)ocr * HDIM + kg * 8;
                f32x16 oa = {};
#pragma unroll
                for (int q = 0; q < 16; ++q) {   // wave w covers K chunk w*256..
                    int kt = w * 16 + q;
                    short8 af = *(const short8*)(ph + (size_t)kt * 16);
                    short8 bf = *(const short8*)(pwo + (size_t)kt * 16);
                    oa = __builtin_amdgcn_mfma_f32_32x32x16_bf16(af, bf, oa, 0, 0, 0);
                }
#pragma unroll
                for (int r = 0; r < 16; ++r) {
                    int grow = (r & 3) + 8 * (r >> 2) + 4 * kg;
                    G[w][grow][l31] = oa[r];     // partial-K tiles
                }
            }
            __syncthreads();
            if (s < 7) {
#pragma unroll
                for (int e = 0; e < 4; ++e) {
                    int ocl = hb * 4 + e;
                    int ocg = s * 32 + ocl;
                    if (ocg < OUTD) {
                        float v = G[0][pm][ocl] + G[1][pm][ocl]
                                + G[2][pm][ocl] + G[3][pm][ocl] + bOut[e];
                        dout[(size_t)(b0 + pm) * (DECT * OUTD) + (size_t)d * OUTD + ocg] = v;
                        Xdec[(size_t)(b0 + pm) * KXP + ocg] = f2bf(v);
                    }
                }
            }
            gbar(myctr, ++gen * 32);
        }
    }
}

extern "C" void kernel_launch(void* const* d_in, const int* in_sizes, int n_in,
                              void* d_out, int out_size, void* d_ws, size_t ws_size,
                              hipStream_t stream) {
    const float* src   = (const float*)d_in[0];
    // d_in[1] = tgt (unused in eval forward)
    const float* W_ih  = (const float*)d_in[2];
    const float* W_hh  = (const float*)d_in[3];
    const float* b_ih  = (const float*)d_in[4];
    const float* b_hh  = (const float*)d_in[5];
    const float* W_out = (const float*)d_in[6];
    const float* b_out = (const float*)d_in[7];
    float* out = (float*)d_out;

    char* ws = (char*)d_ws;
    u16*      srcbf = (u16*)(ws + OFF_SRCBF);
    u16*      H     = (u16*)(ws + OFF_H);
    u16*      Xdec  = (u16*)(ws + OFF_XDEC);
    u16*      Wcat  = (u16*)(ws + OFF_WCAT);
    u16*      Wo    = (u16*)(ws + OFF_WO);
    unsigned* bar   = (unsigned*)(ws + OFF_BAR);

    hipLaunchKernelGGL(prep_kernel, dim3(1024), dim3(256), 0, stream,
                       src, W_ih, W_hh, W_out, srcbf, H, Xdec, Wcat, Wo, bar);

    hipLaunchKernelGGL(lstm_persist, dim3(NWG), dim3(256), 0, stream,
                       srcbf, H, Xdec, Wcat, Wo, b_ih, b_hh, b_out, out, bar);
}

// Round 6
// 2073.693 us; speedup vs baseline: 3.7205x; 2.1771x over previous
//
#include <hip/hip_runtime.h>
#include <hip/hip_bf16.h>

typedef unsigned short u16;
typedef unsigned long long u64;
typedef __attribute__((ext_vector_type(4)))  float  f32x4;
typedef __attribute__((ext_vector_type(8)))  short  short8;
typedef __attribute__((ext_vector_type(16))) float  f32x16;

#define MB     256      // batch
#define SRCT   120      // encoder steps
#define DECT   24       // decoder steps
#define NSTEP  (SRCT + DECT)
#define DIN    216      // input dim
#define HDIM   1024     // hidden
#define KXP    224      // padded x segment (216 real + 8 zero)
#define KA     1248     // KXP + HDIM
#define NGATE  4096
#define OUTD   216
#define NKT    78       // 16-wide K tiles (1248/16)
#define NOCT   156      // 8-wide k-octets (28 x-octets + 128 h-octets)
#define NWG    256

// ---- ws layout (bytes) ----
#define OFF_SRCBF 0u                 // [256][120][224] bf16 = 13,762,560
#define OFF_H     13762560u          // [2][256][1024] bf16  =  1,048,576
#define OFF_XDEC  14811136u          // [256][224] bf16      =    114,688
#define OFF_WCAT  14925824u          // [4096][1248] bf16    = 10,223,616
#define OFF_WO    25149440u          // [216][1024] bf16     =    442,368
#define OFF_BAR   25591808u          // 8 groups x 32 slots x 64 B = 16,384

__device__ __forceinline__ u16 f2bf(float f) {
    union { float f; unsigned v; } c; c.f = f;
    return (u16)((c.v + 0x7FFFu + ((c.v >> 16) & 1u)) >> 16);
}
__device__ __forceinline__ float sigm(float x)  { return 1.0f / (1.0f + __expf(-x)); }
__device__ __forceinline__ float tanh_(float x) { return 1.0f - 2.0f / (1.0f + __expf(2.0f * x)); }

// relaxed agent-scope (coherence-point) accessors: sc0 sc1, no fences.
__device__ __forceinline__ u64 aload(const u64* p) {
    return __hip_atomic_load(p, __ATOMIC_RELAXED, __HIP_MEMORY_SCOPE_AGENT);
}
__device__ __forceinline__ void astore(u64* p, u64 v) {
    __hip_atomic_store(p, v, __ATOMIC_RELAXED, __HIP_MEMORY_SCOPE_AGENT);
}

// group barrier: no RMW, no acquire/release fences.
// __syncthreads drains each wave's write-through stores (vmcnt(0) before
// s_barrier), so data is at the coherence point before the flag leaves.
__device__ __forceinline__ void gbar(unsigned* gslots, int s, unsigned gen) {
    __syncthreads();
    if (threadIdx.x == 0)
        __hip_atomic_store(gslots + s * 16, gen, __ATOMIC_RELAXED, __HIP_MEMORY_SCOPE_AGENT);
    if (threadIdx.x < 64) {
        const int idx = (threadIdx.x & 31) * 16;   // lane i polls slot i
        while (__hip_atomic_load(gslots + idx, __ATOMIC_RELAXED, __HIP_MEMORY_SCOPE_AGENT) < gen) {}
    }
    __syncthreads();
}

// ---------------- prep: convert fp32 inputs -> bf16 working buffers ----------------
__global__ void prep_kernel(const float* __restrict__ src,
                            const float* __restrict__ W_ih,
                            const float* __restrict__ W_hh,
                            const float* __restrict__ W_out,
                            u16* __restrict__ srcbf, u16* __restrict__ H,
                            u16* __restrict__ Xdec,  u16* __restrict__ Wcat,
                            u16* __restrict__ Wo,    unsigned* __restrict__ bar) {
    const int nS  = MB * SRCT * KXP;
    const int nW  = NGATE * KA;
    const int nWo = OUTD * HDIM;
    const int nH  = MB * HDIM;     // H buf0 = 0
    const int nXp = MB * 8;        // Xdec pad cols
    const int nB  = 8 * 32 * 16;   // barrier slots
    const int total = nS + nW + nWo + nH + nXp + nB;
    for (int i = blockIdx.x * blockDim.x + threadIdx.x; i < total; i += gridDim.x * blockDim.x) {
        if (i < nS) {
            int b = i / (SRCT * KXP), r = i % (SRCT * KXP);
            int t = r / KXP, col = r % KXP;
            srcbf[i] = (col < DIN) ? f2bf(src[((size_t)b * SRCT + t) * DIN + col]) : (u16)0;
        } else if (i < nS + nW) {
            int j = i - nS;
            int r = j / KA, col = j % KA;
            u16 v = 0;
            if (col < DIN)       v = f2bf(W_ih[(size_t)r * DIN + col]);
            else if (col >= KXP) v = f2bf(W_hh[(size_t)r * HDIM + (col - KXP)]);
            Wcat[j] = v;
        } else if (i < nS + nW + nWo) {
            Wo[i - nS - nW] = f2bf(W_out[i - nS - nW]);
        } else if (i < nS + nW + nWo + nH) {
            H[i - nS - nW - nWo] = 0;
        } else if (i < nS + nW + nWo + nH + nXp) {
            int j = i - nS - nW - nWo - nH;
            Xdec[(j >> 3) * KXP + DIN + (j & 7)] = 0;
        } else {
            bar[i - nS - nW - nWo - nH - nXp] = 0;
        }
    }
}

// ---------------- persistent LSTM, weights pinned in VGPRs ----------------
// group g = bid&7 owns batches [g*32, g*32+32); slice s = bid>>3 owns h-cols
// [s*32, s*32+32) x 4 gates (wave = gate). 8 independent 32-WG barrier
// domains; cross-WG traffic (H, Xdec) via relaxed agent atomics only.
__global__ void __launch_bounds__(256, 1)
lstm_persist(const u16* __restrict__ srcbf, u16* __restrict__ H,
             u16* __restrict__ Xdec, const u16* __restrict__ Wcat,
             const u16* __restrict__ Wo,
             const float* __restrict__ b_ih, const float* __restrict__ b_hh,
             const float* __restrict__ b_out,
             float* __restrict__ dout, unsigned* __restrict__ bar)
{
    __shared__ u16  Ach[NOCT * 32 * 8];   // [koct][m][8]  79,872 B
    __shared__ float G[4][32][33];        // gate/partial exchange, 16,896 B

    const int bid  = blockIdx.x;
    const int g    = bid & 7;
    const int s    = bid >> 3;
    const int b0   = g * 32;
    const int tid  = threadIdx.x;
    const int w    = tid >> 6;     // wave = gate type (i,f,g,o)
    const int lane = tid & 63;
    const int l31  = lane & 31;
    const int kg   = lane >> 5;

    unsigned* gslots = bar + g * 512;   // 32 slots x 64 B per group

    // ---- pin this wave's weight slice in VGPRs/AGPRs (loaded once) ----
    short8 Bfrag[NKT];
    {
        const int wrow = w * 1024 + s * 32 + l31;
        const u16* pw = Wcat + (size_t)wrow * KA + kg * 8;
#pragma unroll
        for (int kt = 0; kt < NKT; ++kt)
            Bfrag[kt] = *(const short8*)(pw + kt * 16);
    }

    // pointwise mapping: thread -> (batch pm, 4 h-cols); biases + c in regs
    const int pm = tid & 31;
    const int hb = tid >> 5;       // 0..7
    float creg[4], bI[4], bF[4], bG_[4], bO[4], bOut[4];
#pragma unroll
    for (int e = 0; e < 4; ++e) {
        creg[e] = 0.f;
        int hcg = s * 32 + hb * 4 + e;
        bI[e]  = b_ih[hcg]        + b_hh[hcg];
        bF[e]  = b_ih[1024 + hcg] + b_hh[1024 + hcg];
        bG_[e] = b_ih[2048 + hcg] + b_hh[2048 + hcg];
        bO[e]  = b_ih[3072 + hcg] + b_hh[3072 + hcg];
        bOut[e] = (s < 7 && hcg < OUTD) ? b_out[hcg] : 0.f;
    }

    unsigned gen = 0;

    for (int t = 0; t < NSTEP; ++t) {
        const u16* Hc = H + (size_t)(t & 1) * MB * HDIM;
        u16*       Hn = H + (size_t)((t + 1) & 1) * MB * HDIM;
        const bool enc = (t <= SRCT);      // t==SRCT: first decoder x = src[:,119,:]
        const u16* xrow = srcbf + (size_t)((t < SRCT) ? t : (SRCT - 1)) * KXP;
        const int  xstr = SRCT * KXP;

        // ---- stage A = [x|h] (32 batches x 1248) into LDS [koct][m][8] ----
        for (int i = 0; i < 20; ++i) {
            int f = tid + (i << 8);
            if (f < NOCT * 32) {
                int oct = f >> 5, m = f & 31;
                union { uint4 v; u64 q[2]; } u;
                if (oct < 28) {
                    if (enc) {
                        u.v = *(const uint4*)(xrow + (size_t)(b0 + m) * xstr + oct * 8);
                    } else {
                        const u64* xp = (const u64*)(Xdec + (size_t)(b0 + m) * KXP) + oct * 2;
                        u.q[0] = aload(xp); u.q[1] = aload(xp + 1);
                    }
                } else {
                    const u64* hp = (const u64*)(Hc + (size_t)(b0 + m) * HDIM) + (oct - 28) * 2;
                    u.q[0] = aload(hp); u.q[1] = aload(hp + 1);
                }
                *(uint4*)&Ach[f * 8] = u.v;
            }
        }
        __syncthreads();

        // ---- gate GEMM: 78 MFMAs vs pinned B ----
        f32x16 acc0 = {}; f32x16 acc1 = {};
#pragma unroll
        for (int kt = 0; kt < NKT; ++kt) {
            short8 af = *(const short8*)&Ach[(((2 * kt + kg) << 5) + l31) * 8];
            if (kt & 1) acc1 = __builtin_amdgcn_mfma_f32_32x32x16_bf16(af, Bfrag[kt], acc1, 0, 0, 0);
            else        acc0 = __builtin_amdgcn_mfma_f32_32x32x16_bf16(af, Bfrag[kt], acc0, 0, 0, 0);
        }

        // gates -> LDS (C/D layout: col=lane&31, row=(r&3)+8*(r>>2)+4*kg)
#pragma unroll
        for (int r = 0; r < 16; ++r) {
            int grow = (r & 3) + 8 * (r >> 2) + 4 * kg;
            G[w][grow][l31] = acc0[r] + acc1[r];
        }
        __syncthreads();

        // ---- pointwise cell; h (4 bf16) -> one relaxed-agent 8 B store ----
        {
            u64 hq; u16* hp = (u16*)&hq;
#pragma unroll
            for (int e = 0; e < 4; ++e) {
                int hcl = hb * 4 + e;
                float gi = G[0][pm][hcl] + bI[e];
                float gf = G[1][pm][hcl] + bF[e];
                float gg = G[2][pm][hcl] + bG_[e];
                float go = G[3][pm][hcl] + bO[e];
                float c  = sigm(gf) * creg[e] + sigm(gi) * tanh_(gg);
                creg[e]  = c;
                hp[e] = f2bf(sigm(go) * tanh_(c));
            }
            astore((u64*)(Hn + (size_t)(b0 + pm) * HDIM + s * 32 + hb * 4), hq);
        }

        gbar(gslots, s, ++gen);

        // ---- decoder: out = h_new @ W_out^T + b_out (7 slices/group) ----
        if (t >= SRCT) {
            const int d = t - SRCT;
            if (s < 7) {
                const int ocg0 = s * 32 + l31;
                const int ocr  = (ocg0 < OUTD) ? ocg0 : (OUTD - 1);
                const u64* ph64 = (const u64*)(Hn + (size_t)(b0 + l31) * HDIM);
                const u16* pwo  = Wo + (size_t)ocr * HDIM + kg * 8;
                f32x16 oa = {};
#pragma unroll
                for (int q = 0; q < 16; ++q) {   // wave w covers K chunk w*256..
                    int kt = w * 16 + q;
                    union { short8 s8; u64 q2[2]; } ua;
                    ua.q2[0] = aload(ph64 + kt * 4 + kg * 2);
                    ua.q2[1] = aload(ph64 + kt * 4 + kg * 2 + 1);
                    short8 bf = *(const short8*)(pwo + (size_t)kt * 16);
                    oa = __builtin_amdgcn_mfma_f32_32x32x16_bf16(ua.s8, bf, oa, 0, 0, 0);
                }
#pragma unroll
                for (int r = 0; r < 16; ++r) {
                    int grow = (r & 3) + 8 * (r >> 2) + 4 * kg;
                    G[w][grow][l31] = oa[r];     // partial-K tiles
                }
            }
            __syncthreads();
            if (s < 7) {
                const int real = (s < 6) || (hb < 6);   // cols >= 216 are pad
                u64 xq; u16* xp = (u16*)&xq;
                f32x4 ov;
#pragma unroll
                for (int e = 0; e < 4; ++e) {
                    int ocl = hb * 4 + e;
                    float v = 0.f;
                    if (real)
                        v = G[0][pm][ocl] + G[1][pm][ocl]
                          + G[2][pm][ocl] + G[3][pm][ocl] + bOut[e];
                    xp[e] = real ? f2bf(v) : (u16)0;
                    ov[e] = v;
                }
                astore((u64*)(Xdec + (size_t)(b0 + pm) * KXP + s * 32 + hb * 4), xq);
                if (real)
                    *(f32x4*)(dout + (size_t)(b0 + pm) * (DECT * OUTD)
                              + (size_t)d * OUTD + s * 32 + hb * 4) = ov;
            }
            gbar(gslots, s, ++gen);
        }
    }
}

extern "C" void kernel_launch(void* const* d_in, const int* in_sizes, int n_in,
                              void* d_out, int out_size, void* d_ws, size_t ws_size,
                              hipStream_t stream) {
    const float* src   = (const float*)d_in[0];
    // d_in[1] = tgt (unused in eval forward)
    const float* W_ih  = (const float*)d_in[2];
    const float* W_hh  = (const float*)d_in[3];
    const float* b_ih  = (const float*)d_in[4];
    const float* b_hh  = (const float*)d_in[5];
    const float* W_out = (const float*)d_in[6];
    const float* b_out = (const float*)d_in[7];
    float* out = (float*)d_out;

    char* ws = (char*)d_ws;
    u16*      srcbf = (u16*)(ws + OFF_SRCBF);
    u16*      H     = (u16*)(ws + OFF_H);
    u16*      Xdec  = (u16*)(ws + OFF_XDEC);
    u16*      Wcat  = (u16*)(ws + OFF_WCAT);
    u16*      Wo    = (u16*)(ws + OFF_WO);
    unsigned* bar   = (unsigned*)(ws + OFF_BAR);

    hipLaunchKernelGGL(prep_kernel, dim3(1024), dim3(256), 0, stream,
                       src, W_ih, W_hh, W_out, srcbf, H, Xdec, Wcat, Wo, bar);

    hipLaunchKernelGGL(lstm_persist, dim3(NWG), dim3(256), 0, stream,
                       srcbf, H, Xdec, Wcat, Wo, b_ih, b_hh, b_out, out, bar);
}

// Round 7
// 1231.714 us; speedup vs baseline: 6.2637x; 1.6836x over previous
//
#include <hip/hip_runtime.h>
#include <hip/hip_bf16.h>

typedef unsigned short u16;
typedef unsigned int   u32;
typedef unsigned long long u64;
typedef __attribute__((ext_vector_type(4)))  float  f32x4;
typedef __attribute__((ext_vector_type(8)))  short  short8;
typedef __attribute__((ext_vector_type(16))) float  f32x16;

#define MB     256
#define SRCT   120
#define DECT   24
#define NSTEP  144
#define DIN    216
#define HDIM   1024
#define KXP    224      // padded x segment
#define KA     1248
#define NGATE  4096
#define OUTD   216
#define NKT    78       // 16-wide K tiles
#define NWG    256

// ---- ws layout (bytes) ----
// srcbfT [t120][g8][oct28][m32][8] bf16 ; HT 2x[g8][oct128][m32][8] bf16
// XdT [g8][oct28][m32][8] bf16 ; Wcat [4096][1248] bf16 ; Wo [216][1024] bf16
#define OFF_SRCBF 0u
#define OFF_H     13762560u
#define OFF_XDEC  14811136u
#define OFF_WCAT  14925824u
#define OFF_WO    25149440u
#define OFF_BAR   25591808u

__device__ __forceinline__ u16 f2bf(float f) {
    union { float f; unsigned v; } c; c.f = f;
    return (u16)((c.v + 0x7FFFu + ((c.v >> 16) & 1u)) >> 16);
}
__device__ __forceinline__ float sigm(float x)  { return 1.0f / (1.0f + __expf(-x)); }
__device__ __forceinline__ float tanh_(float x) { return 1.0f - 2.0f / (1.0f + __expf(2.0f * x)); }

__device__ __forceinline__ u64 aload(const u64* p) {
    return __hip_atomic_load(p, __ATOMIC_RELAXED, __HIP_MEMORY_SCOPE_AGENT);
}
__device__ __forceinline__ void astore(u64* p, u64 v) {
    __hip_atomic_store(p, v, __ATOMIC_RELAXED, __HIP_MEMORY_SCOPE_AGENT);
}

// 32-WG group barrier: per-WG slot store + parallel poll; no RMW, no fences.
__device__ __forceinline__ void gbar(u32* gslots, int s, u32 gen) {
    __syncthreads();   // drains vmcnt -> write-through stores are at L3
    if (threadIdx.x == 0)
        __hip_atomic_store(gslots + s * 16, gen, __ATOMIC_RELAXED, __HIP_MEMORY_SCOPE_AGENT);
    if (threadIdx.x < 64) {
        const int idx = (threadIdx.x & 31) * 16;
        while (__hip_atomic_load(gslots + idx, __ATOMIC_RELAXED, __HIP_MEMORY_SCOPE_AGENT) < gen) {}
    }
    __syncthreads();
}

// ---------------- prep: fp32 -> bf16, transposed comm layouts ----------------
__global__ void prep_kernel(const float* __restrict__ src,
                            const float* __restrict__ W_ih,
                            const float* __restrict__ W_hh,
                            const float* __restrict__ W_out,
                            u16* __restrict__ srcbf, u16* __restrict__ H,
                            u16* __restrict__ Xd,    u16* __restrict__ Wcat,
                            u16* __restrict__ Wo,    u32* __restrict__ bar) {
    const int nS  = SRCT * 8 * 28 * 256;   // 6,881,280
    const int nW  = NGATE * KA;            // 5,111,808
    const int nWo = OUTD * HDIM;           // 221,184
    const int nH  = MB * HDIM;             // 262,144 (buf0 = h0 = 0)
    const int nXd = 8 * 28 * 256;          // 57,344
    const int nB  = 4096;
    const int total = nS + nW + nWo + nH + nXd + nB;
    for (int i = blockIdx.x * blockDim.x + threadIdx.x; i < total; i += gridDim.x * blockDim.x) {
        if (i < nS) {
            int r = i & 255, i2 = i >> 8;
            int m = r >> 3, e = r & 7;
            int oct = i2 % 28, q = i2 / 28;
            int gi = q & 7, t = q >> 3;
            int col = oct * 8 + e, b = gi * 32 + m;
            srcbf[i] = (col < DIN) ? f2bf(src[((size_t)b * SRCT + t) * DIN + col]) : (u16)0;
        } else if (i < nS + nW) {
            int j = i - nS;
            int r = j / KA, col = j % KA;
            u16 v = 0;
            if (col < DIN)       v = f2bf(W_ih[(size_t)r * DIN + col]);
            else if (col >= KXP) v = f2bf(W_hh[(size_t)r * HDIM + (col - KXP)]);
            Wcat[j] = v;
        } else if (i < nS + nW + nWo) {
            int j = i - nS - nW;
            Wo[j] = f2bf(W_out[j]);
        } else if (i < nS + nW + nWo + nH) {
            H[i - nS - nW - nWo] = 0;
        } else if (i < nS + nW + nWo + nH + nXd) {
            Xd[i - nS - nW - nWo - nH] = 0;
        } else {
            bar[i - nS - nW - nWo - nH - nXd] = 0;
        }
    }
}

// ---------------- persistent LSTM ----------------
// group g = bid&7: batches [g*32,g*32+32). slice s = bid>>3: h-cols [s*32,+32)
// x 4 gates. Waves K-split the gate GEMM (B pinned in VGPRs, all 4 gates).
__global__ void __launch_bounds__(256, 1)
lstm_persist(const u16* __restrict__ srcbf, u16* __restrict__ H,
             u16* __restrict__ Xd, const u16* __restrict__ Wcat,
             const u16* __restrict__ Wo,
             const float* __restrict__ b_ih, const float* __restrict__ b_hh,
             const float* __restrict__ b_out,
             float* __restrict__ dout, u32* __restrict__ bar)
{
    __shared__ __align__(16) u16  Ach[156 * 32 * 8];   // [oct][m][8]  79,872 B
    __shared__ __align__(16) float G2[16 * 32 * 36];   // [slab16][col32][batch36] 73,728 B
    __shared__ __align__(16) u16  Hx[4 * 32 * 8];      // exchange tile 2 KB

    const int bid  = blockIdx.x;
    const int g    = bid & 7;
    const int s    = bid >> 3;
    const int b0   = g * 32;
    const int tid  = threadIdx.x;
    const int p    = tid >> 6;     // wave id (K-split)
    const int lane = tid & 63;
    const int l31  = lane & 31;
    const int kg   = lane >> 5;

    u32* gslots = bar + g * 512;

    // K-split: waves cover 20/20/19/19 k-tiles
    const int ktb = p * 20 - (p == 3 ? 1 : 0);
    const int ktc = (p < 2) ? 20 : 19;

    // ---- pin B for all 4 gates, this wave's k-range (loaded once) ----
    short8 Bfrag[4][20];
#pragma unroll
    for (int gg = 0; gg < 4; ++gg) {
        const u16* pw = Wcat + (size_t)(gg * 1024 + s * 32 + l31) * KA + kg * 8;
#pragma unroll
        for (int j = 0; j < 20; ++j) {
            int kt = ktb + j; if (kt > 77) kt = 77;   // in-bounds junk, never used
            Bfrag[gg][j] = *(const short8*)(pw + kt * 16);
        }
    }

    // pointwise mapping: thread -> (col cs, 4 batches bq*4..)
    const int cs = tid & 31;
    const int bq = tid >> 5;
    float creg[4] = {0.f, 0.f, 0.f, 0.f};
    const int hcg = s * 32 + cs;
    const float bI  = b_ih[hcg]        + b_hh[hcg];
    const float bF  = b_ih[1024 + hcg] + b_hh[1024 + hcg];
    const float bG_ = b_ih[2048 + hcg] + b_hh[2048 + hcg];
    const float bO  = b_ih[3072 + hcg] + b_hh[3072 + hcg];
    const float bOutv = (s < 7 && hcg < OUTD) ? b_out[hcg] : 0.f;

    u32 gen = 0;

    for (int t = 0; t < NSTEP; ++t) {
        const u16* HTc = H + (size_t)(t & 1) * (MB * HDIM);
        u16*       HTn = H + (size_t)((t + 1) & 1) * (MB * HDIM);

        if (t <= SRCT) {
            // ---- stage x from srcbfT (plain, coalesced) ----
            int tt = (t < SRCT) ? t : (SRCT - 1);
            const uint4* xsrc = (const uint4*)(srcbf + (size_t)((tt * 8 + g) * 28) * 256);
#pragma unroll
            for (int j = 0; j < 3; ++j) {
                uint4 v = xsrc[tid + j * 256];
                *(uint4*)(Ach + (size_t)(tid + j * 256) * 8) = v;
            }
            if (tid < 128) {
                uint4 v = xsrc[tid + 768];
                *(uint4*)(Ach + (size_t)(tid + 768) * 8) = v;
            }
            // ---- stage h from HT group slice (agent loads, coalesced) ----
            const u64* hsrc = (const u64*)(HTc + (size_t)g * 32768);
            u64* hdst = (u64*)(Ach + 7168);
#pragma unroll
            for (int ph = 0; ph < 4; ++ph) {
                u64 tmp[8];
#pragma unroll
                for (int j = 0; j < 8; ++j) tmp[j] = aload(hsrc + tid + (ph * 8 + j) * 256);
#pragma unroll
                for (int j = 0; j < 8; ++j) hdst[tid + (ph * 8 + j) * 256] = tmp[j];
            }
        }
        __syncthreads();

        // ---- gate GEMM: per wave ~20 A-frags x 4 gate-MFMAs ----
        f32x16 acc[4] = {f32x16{}, f32x16{}, f32x16{}, f32x16{}};
#pragma unroll
        for (int j = 0; j < 20; ++j) {
            if (j < ktc) {
                int oct = 2 * (ktb + j) + kg;
                short8 af = *(const short8*)(Ach + (size_t)(oct * 32 + l31) * 8);
                acc[0] = __builtin_amdgcn_mfma_f32_32x32x16_bf16(af, Bfrag[0][j], acc[0], 0, 0, 0);
                acc[1] = __builtin_amdgcn_mfma_f32_32x32x16_bf16(af, Bfrag[1][j], acc[1], 0, 0, 0);
                acc[2] = __builtin_amdgcn_mfma_f32_32x32x16_bf16(af, Bfrag[2][j], acc[2], 0, 0, 0);
                acc[3] = __builtin_amdgcn_mfma_f32_32x32x16_bf16(af, Bfrag[3][j], acc[3], 0, 0, 0);
            }
        }
        // partials -> G2[slab=gg*4+p][col=l31][batch], b128 along batch
#pragma unroll
        for (int gg = 0; gg < 4; ++gg) {
#pragma unroll
            for (int rq = 0; rq < 4; ++rq) {
                f32x4 v;
                v[0] = acc[gg][rq * 4 + 0]; v[1] = acc[gg][rq * 4 + 1];
                v[2] = acc[gg][rq * 4 + 2]; v[3] = acc[gg][rq * 4 + 3];
                *(f32x4*)&G2[(size_t)((gg * 4 + p) * 32 + l31) * 36 + rq * 8 + kg * 4] = v;
            }
        }
        __syncthreads();

        // ---- pointwise cell: thread = (col cs, batches bq*4..+3) ----
        {
            f32x4 sg[4];
#pragma unroll
            for (int gg = 0; gg < 4; ++gg) {
                f32x4 a = *(const f32x4*)&G2[(size_t)((gg * 4 + 0) * 32 + cs) * 36 + bq * 4];
#pragma unroll
                for (int pp = 1; pp < 4; ++pp)
                    a += *(const f32x4*)&G2[(size_t)((gg * 4 + pp) * 32 + cs) * 36 + bq * 4];
                sg[gg] = a;
            }
#pragma unroll
            for (int i = 0; i < 4; ++i) {
                float gi = sg[0][i] + bI, gf = sg[1][i] + bF;
                float gG = sg[2][i] + bG_, go = sg[3][i] + bO;
                float c = sigm(gf) * creg[i] + sigm(gi) * tanh_(gG);
                creg[i] = c;
                Hx[(cs >> 3) * 256 + (bq * 4 + i) * 8 + (cs & 7)] = f2bf(sigm(go) * tanh_(c));
            }
        }
        __syncthreads();
        // coalesced write-through of this WG's h slice (4 octets x 32 batches)
        {
            u64 v = ((const u64*)Hx)[tid];
            astore((u64*)HTn + (size_t)g * 8192 + s * 256 + tid, v);
        }
        gbar(gslots, s, ++gen);

        // ---- decoder: restage h, out-GEMM, x exchange ----
        if (t >= SRCT) {
            const int d = t - SRCT;
            // restage h_{t+1} (needed by everyone for next gate GEMM + out)
            const u64* hs2 = (const u64*)(HTn + (size_t)g * 32768);
            u64* hdst = (u64*)(Ach + 7168);
#pragma unroll
            for (int ph = 0; ph < 4; ++ph) {
                u64 tmp[8];
#pragma unroll
                for (int j = 0; j < 8; ++j) tmp[j] = aload(hs2 + tid + (ph * 8 + j) * 256);
#pragma unroll
                for (int j = 0; j < 8; ++j) hdst[tid + (ph * 8 + j) * 256] = tmp[j];
            }
            __syncthreads();
            if (s < 7) {
                f32x16 oacc = {};
                const int orow = (s * 32 + l31 < OUTD) ? (s * 32 + l31) : (OUTD - 1);
                const u16* wob = Wo + (size_t)orow * HDIM + kg * 8;
#pragma unroll
                for (int j = 0; j < 16; ++j) {
                    int kt = p * 16 + j;
                    short8 af = *(const short8*)(Ach + (size_t)((28 + 2 * kt + kg) * 32 + l31) * 8);
                    short8 bf = *(const short8*)(wob + (size_t)kt * 16);
                    oacc = __builtin_amdgcn_mfma_f32_32x32x16_bf16(af, bf, oacc, 0, 0, 0);
                }
#pragma unroll
                for (int rq = 0; rq < 4; ++rq) {
                    f32x4 v;
                    v[0] = oacc[rq * 4 + 0]; v[1] = oacc[rq * 4 + 1];
                    v[2] = oacc[rq * 4 + 2]; v[3] = oacc[rq * 4 + 3];
                    *(f32x4*)&G2[(size_t)(p * 32 + l31) * 36 + rq * 8 + kg * 4] = v;
                }
            }
            __syncthreads();
            if (s < 7) {
                const int  ocol = s * 32 + cs;
                const bool real = ocol < OUTD;
                f32x4 S = *(const f32x4*)&G2[(size_t)(0 * 32 + cs) * 36 + bq * 4];
#pragma unroll
                for (int pp = 1; pp < 4; ++pp)
                    S += *(const f32x4*)&G2[(size_t)(pp * 32 + cs) * 36 + bq * 4];
#pragma unroll
                for (int i = 0; i < 4; ++i) {
                    float v = real ? (S[i] + bOutv) : 0.f;
                    Hx[(cs >> 3) * 256 + (bq * 4 + i) * 8 + (cs & 7)] = real ? f2bf(v) : (u16)0;
                    if (real)
                        dout[(size_t)(b0 + bq * 4 + i) * (DECT * OUTD) + (size_t)d * OUTD + ocol] = v;
                }
            }
            __syncthreads();
            if (s < 7) {
                u64 v = ((const u64*)Hx)[tid];
                astore((u64*)Xd + (size_t)g * 1792 + s * 256 + tid, v);
            }
            gbar(gslots, s, ++gen);
            // stage x_{t+1} from XdT (agent loads, coalesced): 1792 u64
            {
                const u64* xs = (const u64*)Xd + (size_t)g * 1792;
                u64* xd = (u64*)Ach;
                u64 tq[4];
#pragma unroll
                for (int j = 0; j < 4; ++j) tq[j] = aload(xs + tid + j * 256);
#pragma unroll
                for (int j = 0; j < 4; ++j) xd[tid + j * 256] = tq[j];
#pragma unroll
                for (int j = 0; j < 3; ++j) tq[j] = aload(xs + tid + (4 + j) * 256);
#pragma unroll
                for (int j = 0; j < 3; ++j) xd[tid + (4 + j) * 256] = tq[j];
            }
            __syncthreads();
        }
    }
}

extern "C" void kernel_launch(void* const* d_in, const int* in_sizes, int n_in,
                              void* d_out, int out_size, void* d_ws, size_t ws_size,
                              hipStream_t stream) {
    const float* src   = (const float*)d_in[0];
    // d_in[1] = tgt (unused in eval forward)
    const float* W_ih  = (const float*)d_in[2];
    const float* W_hh  = (const float*)d_in[3];
    const float* b_ih  = (const float*)d_in[4];
    const float* b_hh  = (const float*)d_in[5];
    const float* W_out = (const float*)d_in[6];
    const float* b_out = (const float*)d_in[7];
    float* out = (float*)d_out;

    char* ws = (char*)d_ws;
    u16* srcbf = (u16*)(ws + OFF_SRCBF);
    u16* H     = (u16*)(ws + OFF_H);
    u16* Xd    = (u16*)(ws + OFF_XDEC);
    u16* Wcat  = (u16*)(ws + OFF_WCAT);
    u16* Wo    = (u16*)(ws + OFF_WO);
    u32* bar   = (u32*)(ws + OFF_BAR);

    hipLaunchKernelGGL(prep_kernel, dim3(2048), dim3(256), 0, stream,
                       src, W_ih, W_hh, W_out, srcbf, H, Xd, Wcat, Wo, bar);

    hipLaunchKernelGGL(lstm_persist, dim3(NWG), dim3(256), 0, stream,
                       srcbf, H, Xd, Wcat, Wo, b_ih, b_hh, b_out, out, bar);
}